// Round 7
// baseline (135.195 us; speedup 1.0000x reference)
//
#include <hip/hip_runtime.h>

// CenterLossForward:
//   loss        = LAMBDA/BATCH * sum_b ||batch_b - centers[y_b]||^2
//   new_centers = centers; new_centers[y_b] += ALPHA*(batch_b - centers[y_b])  (dups accumulate)
// d_out layout: [loss (1 float)] [new_centers (NUM_CLASSES*EMBED floats)]
//
// R7 copy: no shfl, no divergence. Per group g: two overlapping ALIGNED 16B
// loads (src4[g], src4[g+1] — the latter is the neighbor lane's line, L1 hit),
// assemble {v0.w, v1.x, v1.y, v1.z}, aligned 16B store to dst4[1+g].
// Unroll x4 windows, all loads issued before stores -> 8 loads in flight/wave.

constexpr int   NUM_CLASSES = 100000;
constexpr int   EMBED       = 512;
constexpr int   BATCH       = 4096;
constexpr float LAMBDA      = 0.01f;
constexpr float ALPHA       = 0.1f;

constexpr long  NFLOAT = (long)NUM_CLASSES * EMBED;   // 51,200,000
constexpr long  NGRP   = (NFLOAT - 3) / 4;            // 12,799,999 full dst float4 groups
constexpr long  NSRC4  = NFLOAT / 4;                  // 12,800,000 src float4 words
// note: NGRP == NSRC4 - 1, so g < NGRP implies g+1 < NSRC4 (no tail guard needed)

typedef float f4 __attribute__((ext_vector_type(4)));

__global__ void link_kernel(const int* __restrict__ y, int* __restrict__ head,
                            int* __restrict__ nxt) {
    int s = blockIdx.x * blockDim.x + threadIdx.x;
    if (s < BATCH) nxt[s] = atomicExch(&head[y[s]], s);
}

__global__ void __launch_bounds__(256) copy_dual_kernel(
        const f4* __restrict__ src4, f4* __restrict__ dst4,
        const float* __restrict__ src, float* __restrict__ dst) {
    const int  lane = threadIdx.x & 63;
    const long gw   = (long)((blockIdx.x * blockDim.x + threadIdx.x) >> 6);
    const long nw   = (long)((gridDim.x * blockDim.x) >> 6);

    for (long base = gw * 256; base < NGRP; base += nw * 256) {
        f4 a0, a1, a2, a3, b0, b1, b2, b3;
        const long g0 = base + lane;
        const long g1 = g0 + 64;
        const long g2 = g0 + 128;
        const long g3 = g0 + 192;
        const bool v0 = (g0 < NGRP), v1 = (g1 < NGRP),
                   v2 = (g2 < NGRP), v3 = (g3 < NGRP);

        if (v0) { a0 = src4[g0]; b0 = src4[g0 + 1]; }
        if (v1) { a1 = src4[g1]; b1 = src4[g1 + 1]; }
        if (v2) { a2 = src4[g2]; b2 = src4[g2 + 1]; }
        if (v3) { a3 = src4[g3]; b3 = src4[g3 + 1]; }

        if (v0) dst4[1 + g0] = (f4){a0.w, b0.x, b0.y, b0.z};
        if (v1) dst4[1 + g1] = (f4){a1.w, b1.x, b1.y, b1.z};
        if (v2) dst4[1 + g2] = (f4){a2.w, b2.x, b2.y, b2.z};
        if (v3) dst4[1 + g3] = (f4){a3.w, b3.x, b3.y, b3.z};
    }

    // edges: new_centers floats 0,1,2 and the final float
    if (blockIdx.x == 0 && threadIdx.x == 0) {
        dst[1] = src[0];
        dst[2] = src[1];
        dst[3] = src[2];
        dst[NFLOAT] = src[NFLOAT - 1];
    }
}

// Rewrite touched rows + loss. Runs AFTER copy (same stream) so its row
// stores win the write-after-write.
__global__ void __launch_bounds__(256) update_rows_kernel(
        const float* __restrict__ batch,
        const float* __restrict__ centers,
        const int* __restrict__ head,
        const int* __restrict__ nxt,
        float* __restrict__ out) {
    const int lane = threadIdx.x & 63;
    const int wid  = threadIdx.x >> 6;
    const int gw   = blockIdx.x * 4 + wid;
    const int nw   = gridDim.x * 4;

    float lacc = 0.f;
    for (int r = gw; r < NUM_CLASSES; r += nw) {
        int s = head[r];                       // wave-uniform
        if (s < 0) continue;

        const float* crow = centers + (size_t)r * EMBED;
        float c[8], a[8];
        #pragma unroll
        for (int k = 0; k < 8; ++k) { c[k] = crow[lane + 64 * k]; a[k] = 0.f; }

        while (s >= 0) {
            const float* brow = batch + (size_t)s * EMBED;
            #pragma unroll
            for (int k = 0; k < 8; ++k) {
                float d = brow[lane + 64 * k] - c[k];
                a[k] += d;
                lacc += d * d;
            }
            s = nxt[s];
        }

        float* orow = out + 1 + (size_t)r * EMBED;
        #pragma unroll
        for (int k = 0; k < 8; ++k) orow[lane + 64 * k] = c[k] + ALPHA * a[k];
    }

    #pragma unroll
    for (int off = 32; off > 0; off >>= 1) lacc += __shfl_xor(lacc, off, 64);
    if (lane == 0 && lacc != 0.f) atomicAdd(out, lacc * (LAMBDA / (float)BATCH));
}

// ---- fallback (ws too small): blit + per-sample atomics ----
__global__ void center_update_fallback(const int* __restrict__ y,
                                       const float4* __restrict__ batch,
                                       const float4* __restrict__ centers,
                                       float* __restrict__ out) {
    const int b = blockIdx.x, t = threadIdx.x;
    const int cls = y[b];
    const float4 xb = batch[(size_t)b * (EMBED / 4) + t];
    const float4 c  = centers[(size_t)cls * (EMBED / 4) + t];
    const float dx = xb.x - c.x, dy = xb.y - c.y, dz = xb.z - c.z, dw = xb.w - c.w;
    float* orow = out + 1 + (size_t)cls * EMBED + (size_t)t * 4;
    atomicAdd(orow + 0, ALPHA * dx);
    atomicAdd(orow + 1, ALPHA * dy);
    atomicAdd(orow + 2, ALPHA * dz);
    atomicAdd(orow + 3, ALPHA * dw);
    float s = dx * dx + dy * dy + dz * dz + dw * dw;
    #pragma unroll
    for (int off = 32; off > 0; off >>= 1) s += __shfl_down(s, off, 64);
    __shared__ float wsum[2];
    const int lane = t & 63, wid = t >> 6;
    if (lane == 0) wsum[wid] = s;
    __syncthreads();
    if (t == 0) atomicAdd(out, (wsum[0] + wsum[1]) * (LAMBDA / (float)BATCH));
}

extern "C" void kernel_launch(void* const* d_in, const int* in_sizes, int n_in,
                              void* d_out, int out_size, void* d_ws, size_t ws_size,
                              hipStream_t stream) {
    const int*   y       = (const int*)d_in[0];
    const float* batch   = (const float*)d_in[1];
    const float* centers = (const float*)d_in[2];
    float*       out     = (float*)d_out;

    const size_t head_bytes = (size_t)NUM_CLASSES * sizeof(int);
    const size_t next_bytes = (size_t)BATCH * sizeof(int);

    (void)hipMemsetAsync(out, 0, sizeof(float), stream);  // loss accumulator

    if (ws_size >= head_bytes + next_bytes) {
        int* head = (int*)d_ws;
        int* nxt  = (int*)((char*)d_ws + head_bytes);

        (void)hipMemsetAsync(head, 0xFF, head_bytes, stream);
        link_kernel<<<(BATCH + 255) / 256, 256, 0, stream>>>(y, head, nxt);
        copy_dual_kernel<<<2048, 256, 0, stream>>>(
            (const f4*)centers, (f4*)out, centers, out);
        update_rows_kernel<<<1024, 256, 0, stream>>>(batch, centers, head, nxt, out);
    } else {
        (void)hipMemcpyAsync(out + 1, centers, NFLOAT * sizeof(float),
                             hipMemcpyDeviceToDevice, stream);
        center_update_fallback<<<BATCH, EMBED / 4, 0, stream>>>(
            y, (const float4*)batch, (const float4*)centers, out);
    }
}

// Round 8
// 119.713 us; speedup vs baseline: 1.1293x; 1.1293x over previous
//
#include <hip/hip_runtime.h>

// CenterLossForward:
//   loss        = LAMBDA/BATCH * sum_b ||batch_b - centers[y_b]||^2
//   new_centers = centers; new_centers[y_b] += ALPHA*(batch_b - centers[y_b])  (dups accumulate)
// d_out layout: [loss (1 float)] [new_centers (NUM_CLASSES*EMBED floats)]
//
// R8 copy: LDS-bounce. Global loads and stores are BOTH fully 16B-aligned
// sequential float4 streams (the m13 6.3TB/s pattern); the 1-float shift is
// absorbed by shifted dword reads from LDS (4-way bank conflict, ~free vs
// 69TB/s LDS ceiling). Stores stay non-temporal (R6: −14us).

constexpr int   NUM_CLASSES = 100000;
constexpr int   EMBED       = 512;
constexpr int   BATCH       = 4096;
constexpr float LAMBDA      = 0.01f;
constexpr float ALPHA       = 0.1f;

constexpr long  NFLOAT = (long)NUM_CLASSES * EMBED;   // 51,200,000
constexpr long  NGRP   = (NFLOAT - 3) / 4;            // 12,799,999 dst float4 groups
constexpr long  NSRC4  = NFLOAT / 4;                  // 12,800,000 src float4 words
constexpr int   TILE_GRP = 1024;                      // float4 groups per LDS tile (16KB)

typedef float f4 __attribute__((ext_vector_type(4)));

__global__ void link_kernel(const int* __restrict__ y, int* __restrict__ head,
                            int* __restrict__ nxt) {
    int s = blockIdx.x * blockDim.x + threadIdx.x;
    if (s < BATCH) nxt[s] = atomicExch(&head[y[s]], s);
}

__global__ void __launch_bounds__(256) copy_lds_kernel(
        const f4* __restrict__ src4, f4* __restrict__ dst4,
        const float* __restrict__ src, float* __restrict__ dst) {
    __shared__ float lds[4 * TILE_GRP + 4];   // +1 boundary word
    const int t = threadIdx.x;
    const long nTiles = (NGRP + TILE_GRP - 1) / TILE_GRP;

    for (long T = blockIdx.x; T < nTiles; T += gridDim.x) {
        const long G = T * TILE_GRP;

        // cooperative ALIGNED float4 loads: src4[G .. G+TILE_GRP] -> LDS
        #pragma unroll
        for (int w = 0; w < 4; ++w) {
            const long g = G + w * 256 + t;
            f4 v = (g < NSRC4) ? src4[g] : (f4){0.f, 0.f, 0.f, 0.f};
            *(f4*)&lds[4 * (w * 256 + t)] = v;
        }
        if (t == 0) {
            const long g = G + TILE_GRP;     // boundary word for the shift
            f4 v = (g < NSRC4) ? src4[g] : (f4){0.f, 0.f, 0.f, 0.f};
            *(f4*)&lds[4 * TILE_GRP] = v;
        }
        __syncthreads();

        // shifted dword reads from LDS, ALIGNED float4 NT store
        #pragma unroll
        for (int w = 0; w < 4; ++w) {
            const long g = G + w * 256 + t;
            if (g < NGRP) {
                const int l = 4 * (w * 256 + t);
                f4 o = {lds[l + 3], lds[l + 4], lds[l + 5], lds[l + 6]};
                __builtin_nontemporal_store(o, &dst4[1 + g]);
            }
        }
        __syncthreads();
    }

    // edges: new_centers floats 0,1,2 and the final float
    if (blockIdx.x == 0 && threadIdx.x == 0) {
        dst[1] = src[0];
        dst[2] = src[1];
        dst[3] = src[2];
        dst[NFLOAT] = src[NFLOAT - 1];
    }
}

// Rewrite touched rows + loss. Runs AFTER copy (same stream) so its row
// stores win the write-after-write.
__global__ void __launch_bounds__(256) update_rows_kernel(
        const float* __restrict__ batch,
        const float* __restrict__ centers,
        const int* __restrict__ head,
        const int* __restrict__ nxt,
        float* __restrict__ out) {
    const int lane = threadIdx.x & 63;
    const int wid  = threadIdx.x >> 6;
    const int gw   = blockIdx.x * 4 + wid;
    const int nw   = gridDim.x * 4;

    float lacc = 0.f;
    for (int r = gw; r < NUM_CLASSES; r += nw) {
        int s = head[r];                       // wave-uniform
        if (s < 0) continue;

        const float* crow = centers + (size_t)r * EMBED;
        float c[8], a[8];
        #pragma unroll
        for (int k = 0; k < 8; ++k) { c[k] = crow[lane + 64 * k]; a[k] = 0.f; }

        while (s >= 0) {
            const float* brow = batch + (size_t)s * EMBED;
            #pragma unroll
            for (int k = 0; k < 8; ++k) {
                float d = brow[lane + 64 * k] - c[k];
                a[k] += d;
                lacc += d * d;
            }
            s = nxt[s];
        }

        float* orow = out + 1 + (size_t)r * EMBED;
        #pragma unroll
        for (int k = 0; k < 8; ++k) orow[lane + 64 * k] = c[k] + ALPHA * a[k];
    }

    #pragma unroll
    for (int off = 32; off > 0; off >>= 1) lacc += __shfl_xor(lacc, off, 64);
    if (lane == 0 && lacc != 0.f) atomicAdd(out, lacc * (LAMBDA / (float)BATCH));
}

// ---- fallback (ws too small): blit + per-sample atomics ----
__global__ void center_update_fallback(const int* __restrict__ y,
                                       const float4* __restrict__ batch,
                                       const float4* __restrict__ centers,
                                       float* __restrict__ out) {
    const int b = blockIdx.x, t = threadIdx.x;
    const int cls = y[b];
    const float4 xb = batch[(size_t)b * (EMBED / 4) + t];
    const float4 c  = centers[(size_t)cls * (EMBED / 4) + t];
    const float dx = xb.x - c.x, dy = xb.y - c.y, dz = xb.z - c.z, dw = xb.w - c.w;
    float* orow = out + 1 + (size_t)cls * EMBED + (size_t)t * 4;
    atomicAdd(orow + 0, ALPHA * dx);
    atomicAdd(orow + 1, ALPHA * dy);
    atomicAdd(orow + 2, ALPHA * dz);
    atomicAdd(orow + 3, ALPHA * dw);
    float s = dx * dx + dy * dy + dz * dz + dw * dw;
    #pragma unroll
    for (int off = 32; off > 0; off >>= 1) s += __shfl_down(s, off, 64);
    __shared__ float wsum[2];
    const int lane = t & 63, wid = t >> 6;
    if (lane == 0) wsum[wid] = s;
    __syncthreads();
    if (t == 0) atomicAdd(out, (wsum[0] + wsum[1]) * (LAMBDA / (float)BATCH));
}

extern "C" void kernel_launch(void* const* d_in, const int* in_sizes, int n_in,
                              void* d_out, int out_size, void* d_ws, size_t ws_size,
                              hipStream_t stream) {
    const int*   y       = (const int*)d_in[0];
    const float* batch   = (const float*)d_in[1];
    const float* centers = (const float*)d_in[2];
    float*       out     = (float*)d_out;

    const size_t head_bytes = (size_t)NUM_CLASSES * sizeof(int);
    const size_t next_bytes = (size_t)BATCH * sizeof(int);

    (void)hipMemsetAsync(out, 0, sizeof(float), stream);  // loss accumulator

    if (ws_size >= head_bytes + next_bytes) {
        int* head = (int*)d_ws;
        int* nxt  = (int*)((char*)d_ws + head_bytes);

        (void)hipMemsetAsync(head, 0xFF, head_bytes, stream);
        link_kernel<<<(BATCH + 255) / 256, 256, 0, stream>>>(y, head, nxt);
        copy_lds_kernel<<<2048, 256, 0, stream>>>(
            (const f4*)centers, (f4*)out, centers, out);
        update_rows_kernel<<<1024, 256, 0, stream>>>(batch, centers, head, nxt, out);
    } else {
        (void)hipMemcpyAsync(out + 1, centers, NFLOAT * sizeof(float),
                             hipMemcpyDeviceToDevice, stream);
        center_update_fallback<<<BATCH, EMBED / 4, 0, stream>>>(
            y, (const float4*)batch, (const float4*)centers, out);
    }
}